// Round 6
// baseline (123.555 us; speedup 1.0000x reference)
//
#include <hip/hip_runtime.h>
#include <math.h>

#define Wd 256
#define Hd 256
#define KW 11
#define OUT_R 26              // output rows per block; stream 36 = 3 chunks of 12
#define RING 12               // ring size 12: slot=(2*jp+c)%12, chunk-independent
#define BLOCK 256

typedef float v2f __attribute__((ext_vector_type(2)));

__device__ __forceinline__ float rfl(float v) {
    return __int_as_float(__builtin_amdgcn_readfirstlane(__float_as_int(v)));
}

// Workgroup barrier that does NOT drain vmcnt (lgkmcnt only): global
// prefetch loads ride across emit steps (R5: small real gain).
__device__ __forceinline__ void barrier_lds_only() {
    asm volatile("s_waitcnt lgkmcnt(0)\n\ts_barrier" ::: "memory");
}

// Vertical-first SSIM with a 1-STEP SKEWED software pipeline (R6).
//
// Measured history:
//   R0  (256,4) intra-step hconv: 43-47us. VALU 40%, LDS ~55%, HBM 14%.
//   R1/R3 launch_bounds arg2 > 4: VGPR squeeze -> spill -> 88/148us. NEVER.
//   R4  more blocks (OUT_R=14): dur scaled with step count, occupancy flat.
//   R5  2-deep global prefetch: -4%. L3-resident dispatch == HBM dispatch
//       duration -> NOT memory-latency-bound. Clock = emit-step serial
//       chain: vconv -> write -> barrier -> (read latency exposed) -> hconv.
//
// R6: at emit e, hconv consumes the buffer written at e-1 (reads issue
// right after the previous barrier, hidden under this step's vconv FMAs);
// then write buf[e&1]; ONE barrier. The old post-barrier ds_read stall is
// gone -- both phases are independent work inside one inter-barrier region.
// Epilogue drains the final buffer after the loop.
// One-arg launch_bounds: vconv+hconv accumulators now coexist (+~16 VGPR);
// any arg2>4 squeezes below need and spills (R1/R3).
__global__ __launch_bounds__(BLOCK) void ssim_pair_kernel(
    const float* __restrict__ img1, const float* __restrict__ img2,
    const float* __restrict__ window, float* __restrict__ out, float scale)
{
    // rbE[buf][row][e+2] holds col 2e  (e=-2..130 -> idx 0..132)
    // rbO[buf][row][o+3] holds col 2o+1 (o=-3..129 -> idx 0..132)
    __shared__ __align__(16) float4 rbE[2][2][136];
    __shared__ __align__(16) float4 rbO[2][2][136];   // 17.4 KB
    __shared__ float red[BLOCK / 64];

    const float C1 = 1e-4f, C2 = 9e-4f;
    const int t = threadIdx.x;
    const int band = blockIdx.x;     // 0..9 (band 9 partial: 22 rows)
    const int plane = blockIdx.y;    // 0..143
    const float* __restrict__ p1 = img1 + (size_t)plane * (Hd * Wd);
    const float* __restrict__ p2 = img2 + (size_t)plane * (Hd * Wd);

    // Separable 1D weights (win2d = a outer a, sum a = 1); pin to SGPRs.
    float wl[KW];
    {
        float c = sqrtf(window[5 * KW + 5]);
        #pragma unroll
        for (int k = 0; k < KW; ++k)
            wl[k] = rfl(window[k * KW + 5] / c);
    }

    // Zero the column-halo cells once (never written by the row pass);
    // first read happens at emit e=1, two barriers later -> visible.
    if (t < 4) {
        int buf = t >> 1, row = t & 1;
        float4 z = make_float4(0.f, 0.f, 0.f, 0.f);
        rbE[buf][row][0] = z; rbE[buf][row][1] = z;
        rbE[buf][row][130] = z; rbE[buf][row][131] = z; rbE[buf][row][132] = z;
        rbO[buf][row][0] = z; rbO[buf][row][1] = z; rbO[buf][row][2] = z;
        rbO[buf][row][131] = z; rbO[buf][row][132] = z;
    }

    const int ghbase = band * OUT_R - 5;   // global row of stream index 0

    v2f rXY[RING], rQP[RING];
    float acc = 0.f;
    int ecount = 0;                        // uniform emit counter (skew phase)
    const int r = t >> 7, cp = t & 127;    // hconv assignment: row, col-pair

    // hconv on buffer pb: 11-tap horizontal conv + SSIM, 2 cols x 1 row per
    // thread (waves 0-1: row 0, waves 2-3: row 1). Accumulates into acc.
    auto hconv = [&](int pb) {
        const float4* bE = &rbE[pb][r][cp];
        const float4* bO = &rbO[pb][r][cp];
        v2f a0, q0, a1, q1;
        a0.x = a0.y = q0.x = q0.y = 0.f;
        a1.x = a1.y = q1.x = q1.y = 0.f;
        #pragma unroll
        for (int k = 0; k < 6; ++k) {
            float4 vO = bO[k];                 // ds_read_b128
            v2f oab; oab.x = vO.x; oab.y = vO.y;
            v2f oqp; oqp.x = vO.z; oqp.y = vO.w;
            a0 += wl[2 * k] * oab;  q0 += wl[2 * k] * oqp;
            if (k >= 1) { a1 += wl[2 * k - 1] * oab;  q1 += wl[2 * k - 1] * oqp; }
            float4 vE = bE[k];                 // ds_read_b128
            v2f eab; eab.x = vE.x; eab.y = vE.y;
            v2f eqp; eqp.x = vE.z; eqp.y = vE.w;
            a1 += wl[2 * k] * eab;  q1 += wl[2 * k] * eqp;
            if (k <= 4) { a0 += wl[2 * k + 1] * eab;  q0 += wl[2 * k + 1] * eqp; }
        }
        {
            float mu1 = a0.x, mu2 = a0.y, sq = q0.x, sp = q0.y;
            float mu1sq = mu1 * mu1, mu2sq = mu2 * mu2, mu12 = mu1 * mu2;
            float musum = mu1sq + mu2sq;
            float num = (2.f * mu12 + C1) * (2.f * (sp - mu12) + C2);
            float den = (musum + C1) * ((sq - musum) + C2);
            acc += num * __builtin_amdgcn_rcpf(den);
        }
        {
            float mu1 = a1.x, mu2 = a1.y, sq = q1.x, sp = q1.y;
            float mu1sq = mu1 * mu1, mu2sq = mu2 * mu2, mu12 = mu1 * mu2;
            float musum = mu1sq + mu2sq;
            float num = (2.f * mu12 + C1) * (2.f * (sp - mu12) + C2);
            float den = (musum + C1) * ((sq - musum) + C2);
            acc += num * __builtin_amdgcn_rcpf(den);
        }
    };

    // 2-deep prefetch pipeline (R5): cur = pair for THIS step, nxt = next.
    float cx0, cy0, cx1, cy1;
    float nx0, ny0, nx1, ny1;
    {
        int g0 = ghbase, g1 = ghbase + 1;
        cx0 = ((unsigned)g0 < (unsigned)Hd) ? p1[(g0 << 8) + t] : 0.f;
        cy0 = ((unsigned)g0 < (unsigned)Hd) ? p2[(g0 << 8) + t] : 0.f;
        cx1 = ((unsigned)g1 < (unsigned)Hd) ? p1[(g1 << 8) + t] : 0.f;
        cy1 = ((unsigned)g1 < (unsigned)Hd) ? p2[(g1 << 8) + t] : 0.f;
        int g2 = ghbase + 2, g3 = ghbase + 3;
        nx0 = ((unsigned)g2 < (unsigned)Hd) ? p1[(g2 << 8) + t] : 0.f;
        ny0 = ((unsigned)g2 < (unsigned)Hd) ? p2[(g2 << 8) + t] : 0.f;
        nx1 = ((unsigned)g3 < (unsigned)Hd) ? p1[(g3 << 8) + t] : 0.f;
        ny1 = ((unsigned)g3 < (unsigned)Hd) ? p2[(g3 << 8) + t] : 0.f;
    }

    #pragma unroll 1
    for (int ch = 0; ch < 3; ++ch) {
        #pragma unroll
        for (int jp = 0; jp < 6; ++jp) {
            const int i0 = 12 * ch + 2 * jp;        // uniform (ch runtime)
            const int s0 = (2 * jp) % RING;         // STATIC slot
            const int s1 = (2 * jp + 1) % RING;     // STATIC slot

            // ring insert rows i0, i0+1 (consume cur; out-of-range = zeros)
            {
                v2f v; v.x = cx0; v.y = cy0; rXY[s0] = v;
                v2f q; q.x = fmaf(cx0, cx0, cy0 * cy0); q.y = cx0 * cy0; rQP[s0] = q;
                v2f v2; v2.x = cx1; v2.y = cy1; rXY[s1] = v2;
                v2f q2; q2.x = fmaf(cx1, cx1, cy1 * cy1); q2.y = cx1 * cy1; rQP[s1] = q2;
            }
            // rotate pipeline, issue loads 2 steps ahead
            cx0 = nx0; cy0 = ny0; cx1 = nx1; cy1 = ny1;
            if (i0 + 4 < 36) {
                int g0 = ghbase + i0 + 4, g1 = ghbase + i0 + 5;
                nx0 = ((unsigned)g0 < (unsigned)Hd) ? p1[(g0 << 8) + t] : 0.f;
                ny0 = ((unsigned)g0 < (unsigned)Hd) ? p2[(g0 << 8) + t] : 0.f;
                nx1 = ((unsigned)g1 < (unsigned)Hd) ? p1[(g1 << 8) + t] : 0.f;
                ny1 = ((unsigned)g1 < (unsigned)Hd) ? p2[(g1 << 8) + t] : 0.f;
            }

            const int orow0 = band * OUT_R + i0 - 10;     // uniform
            if (i0 >= 10 && orow0 < Hd) {   // emit rows i0, i0+1
                const int wb = ecount & 1;  // write buffer (runtime, uniform)
                // vertical 11-tap conv: row i0 slots (2jp+2+m)%12,
                //                       row i0+1 slots (2jp+3+m)%12 — STATIC
                v2f vAB0, vQP0, vAB1, vQP1;
                vAB0.x = vAB0.y = vQP0.x = vQP0.y = 0.f;
                vAB1.x = vAB1.y = vQP1.x = vQP1.y = 0.f;
                #pragma unroll
                for (int m = 0; m < KW; ++m) {
                    const int sa = (2 * jp + 2 + m) % RING;
                    const int sb = (2 * jp + 3 + m) % RING;
                    float w = wl[m];
                    vAB0 += w * rXY[sa];  vQP0 += w * rQP[sa];
                    vAB1 += w * rXY[sb];  vQP1 += w * rQP[sb];
                }

                // SKEW: consume the buffer written at the PREVIOUS emit.
                // Its writes were barrier-separated at the end of that step;
                // reads here have the whole vconv/write phase to hide under.
                if (ecount > 0) hconv(wb ^ 1);

                const int half = t >> 1;
                if (t & 1) {
                    rbO[wb][0][half + 3] = make_float4(vAB0.x, vAB0.y, vQP0.x, vQP0.y);
                    rbO[wb][1][half + 3] = make_float4(vAB1.x, vAB1.y, vQP1.x, vQP1.y);
                } else {
                    rbE[wb][0][half + 2] = make_float4(vAB0.x, vAB0.y, vQP0.x, vQP0.y);
                    rbE[wb][1][half + 2] = make_float4(vAB1.x, vAB1.y, vQP1.x, vQP1.y);
                }
                barrier_lds_only();   // ONE barrier/step; global loads in flight
                ++ecount;
            }
        }
    }

    // epilogue: drain the final emitted pair (written at ecount-1)
    if (ecount > 0) hconv((ecount - 1) & 1);

    // --- block reduction + fused global reduce (atomic) ---
    #pragma unroll
    for (int off = 32; off > 0; off >>= 1)
        acc += __shfl_down(acc, off, 64);
    int wave = t >> 6;
    if ((t & 63) == 0) red[wave] = acc;
    barrier_lds_only();
    if (t == 0) {
        float partial = red[0] + red[1] + red[2] + red[3];
        float v = partial * scale;                 // scale = -1/count
        if (band == 0 && plane == 0) v += 1.0f;    // out = 1 - sum/count
        atomicAdd(out, v);
    }
}

extern "C" void kernel_launch(void* const* d_in, const int* in_sizes, int n_in,
                              void* d_out, int out_size, void* d_ws, size_t ws_size,
                              hipStream_t stream) {
    const float* img1   = (const float*)d_in[0];
    const float* img2   = (const float*)d_in[1];
    const float* window = (const float*)d_in[2];
    float* out = (float*)d_out;

    const int planes = 16 * 9;                     // 144
    const int bands = (Hd + OUT_R - 1) / OUT_R;    // 10 (last band 22 rows)

    hipMemsetAsync(out, 0, sizeof(float), stream);

    const float scale = -(float)(1.0 / ((double)planes * Hd * Wd));
    dim3 grid(bands, planes);
    ssim_pair_kernel<<<grid, BLOCK, 0, stream>>>(img1, img2, window, out, scale);
}

// Round 7
// 118.721 us; speedup vs baseline: 1.0407x; 1.0407x over previous
//
#include <hip/hip_runtime.h>
#include <math.h>

#define Wd 256
#define Hd 256
#define KW 11
#define OUT_R 26              // output rows per block; stream 36 = 9 steps x 4 rows
#define BLOCK 256

typedef float v4f __attribute__((ext_vector_type(4)));

__device__ __forceinline__ float rfl(float v) {
    return __int_as_float(__builtin_amdgcn_readfirstlane(__float_as_int(v)));
}

// lgkmcnt-only barrier: LDS handoff without draining global prefetch (R2/R5).
__device__ __forceinline__ void barrier_lds_only() {
    asm volatile("s_waitcnt lgkmcnt(0)\n\ts_barrier" ::: "memory");
}

// R7: 4-ROW STEPS. Ledger: duration invariant (~42-46us) to barrier flavor
// (R2), block supply (R4), prefetch depth (R5 -4%), intra-step overlap (R6);
// L3-resident dispatch == HBM dispatch -> memory exonerated. R0-vs-R4 fit:
// time ~ step count at fixed ~4100cy/step. So: amortize the fixed per-step
// cost over 4 rows instead of 2. 9 insert steps (vs 18), 7 emits (vs 13).
//
// Ring 16 (4 floats/row): phase p=k&3 fills slots 4p..4p+3 (no wrap).
// Emit at step k (k>=3): band rows rr=4k-12..4k-9 (wave w = emitted row w),
// slots (4p+4+c+m)&15, all static. Emit-only epilogue (virtual k=9, phase 1,
// zero insert for streams 36..37) covers rows 24..25.
//
// LDS: mod-4 column split res[row][col%4][col/4+2] (v4f = vconv a,b,q,p).
// Generalizes the proven E/O split: writes lane-contiguous per residue
// (2-way banks = free, m136); hconv reads 14 b128/thread for 4 cols
// (3.5/output vs 6 before, 1.56x less LDS traffic), all <=2-way.
// Single buffer 17.4KB, write -> bar -> read -> bar.
//
// launch_bounds(256,3): VGPR budget ~170 >= est need (~130: 64-reg ring +
// accs). (256,6)/(256,8) squeezed below need and spilled 65-167MB (R1/R3) --
// never set arg2 above what the natural allocation fits.
__global__ __launch_bounds__(BLOCK, 3) void ssim_quad_kernel(
    const float* __restrict__ img1, const float* __restrict__ img2,
    const float* __restrict__ window, float* __restrict__ out, float scale)
{
    // res[emit row 0..3][col&3][col>>2 + 2]; idx 0,1,66,67 = zero halos
    __shared__ __align__(16) v4f res[4][4][68];   // 17.4 KB
    __shared__ float red[BLOCK / 64];

    const float C1 = 1e-4f, C2 = 9e-4f;
    const int t = threadIdx.x;
    const int band = blockIdx.x;     // 0..9 (band 9 partial: 22 rows)
    const int plane = blockIdx.y;    // 0..143
    const float* __restrict__ p1 = img1 + (size_t)plane * (Hd * Wd);
    const float* __restrict__ p2 = img2 + (size_t)plane * (Hd * Wd);

    // Separable 1D weights; pin to SGPRs.
    float wl[KW];
    {
        float c = sqrtf(window[5 * KW + 5]);
        #pragma unroll
        for (int k = 0; k < KW; ++k)
            wl[k] = rfl(window[k * KW + 5] / c);
    }

    // Zero column-halo cells (idx 0,1,66,67 of each [row][arr]); visible at
    // the first emit's bar1.
    if (t < 64) {
        int row = t >> 4, arr = (t >> 2) & 3, sel = t & 3;
        int idx = (sel < 2) ? sel : (64 + sel);
        v4f z = {0.f, 0.f, 0.f, 0.f};
        res[row][arr][idx] = z;
    }

    const int ghbase = band * OUT_R - 5;   // global row of stream index 0
    const int w = t >> 6, cp = t & 63;     // hconv: wave=row, 4 cols/thread

    v4f rng[16];                           // ring: (x, y, x^2+y^2, x*y)
    float acc = 0.f;

    auto ssim_term = [&](v4f a) -> float {
        float mu1 = a.x, mu2 = a.y, sq = a.z, sp = a.w;
        float mu12 = mu1 * mu2;
        float musum = mu1 * mu1 + mu2 * mu2;
        float num = (2.f * mu12 + C1) * (2.f * (sp - mu12) + C2);
        float den = (musum + C1) * ((sq - musum) + C2);
        return num * __builtin_amdgcn_rcpf(den);
    };

    // initial 4-row load (stream rows 0..3); 1-deep prefetch thereafter
    float cx[4], cy[4];
    #pragma unroll
    for (int c = 0; c < 4; ++c) {
        int g = ghbase + c;
        bool ok = (unsigned)g < (unsigned)Hd;
        cx[c] = ok ? p1[(g << 8) + t] : 0.f;
        cy[c] = ok ? p2[(g << 8) + t] : 0.f;
    }

#define SSIM_STEP(PH, K, DOLOAD, DOEMIT) do {                                  \
    _Pragma("unroll")                                                          \
    for (int c = 0; c < 4; ++c) {          /* insert rows 4K..4K+3 */          \
        v4f e;                                                                 \
        e.x = cx[c]; e.y = cy[c];                                              \
        e.z = fmaf(cx[c], cx[c], cy[c] * cy[c]);                               \
        e.w = cx[c] * cy[c];                                                   \
        rng[4 * (PH) + c] = e;                                                 \
    }                                                                          \
    if (DOLOAD) {                          /* prefetch rows 4(K+1).. */        \
        _Pragma("unroll")                                                      \
        for (int c = 0; c < 4; ++c) {                                          \
            int g = ghbase + 4 * ((K) + 1) + c;                                \
            bool ok = (unsigned)g < (unsigned)Hd;                              \
            cx[c] = ok ? p1[(g << 8) + t] : 0.f;                               \
            cy[c] = ok ? p2[(g << 8) + t] : 0.f;                               \
        }                                                                      \
    }                                                                          \
    if (DOEMIT) {                                                              \
        _Pragma("unroll")                                                      \
        for (int c = 0; c < 4; ++c) {      /* vertical 11-tap, 4 rows */       \
            v4f a = {0.f, 0.f, 0.f, 0.f};                                      \
            _Pragma("unroll")                                                  \
            for (int m = 0; m < KW; ++m)                                       \
                a += wl[m] * rng[(4 * (PH) + 4 + c + m) & 15];                 \
            res[c][t & 3][(t >> 2) + 2] = a;   /* col t, residue split */      \
        }                                                                      \
        barrier_lds_only();                                                    \
        {                                                                      \
            const int rr = 4 * (K) - 12 + w;   /* band row of wave w */        \
            if (rr < OUT_R && band * OUT_R + rr < Hd) {                        \
                v4f a0 = {0.f, 0.f, 0.f, 0.f}, a1 = {0.f, 0.f, 0.f, 0.f};      \
                v4f a2 = {0.f, 0.f, 0.f, 0.f}, a3 = {0.f, 0.f, 0.f, 0.f};      \
                _Pragma("unroll")                                              \
                for (int off = -5; off <= 8; ++off) {  /* cols 4cp+off */      \
                    v4f v = res[w][(off) & 3][cp + ((off) >> 2) + 2];          \
                    if ((off) <= 5)                a0 += wl[(off) + 5] * v;    \
                    if ((off) >= -4 && (off) <= 6) a1 += wl[(off) + 4] * v;    \
                    if ((off) >= -3 && (off) <= 7) a2 += wl[(off) + 3] * v;    \
                    if ((off) >= -2)               a3 += wl[(off) + 2] * v;    \
                }                                                              \
                acc += ssim_term(a0); acc += ssim_term(a1);                    \
                acc += ssim_term(a2); acc += ssim_term(a3);                    \
            }                                                                  \
        }                                                                      \
        barrier_lds_only();                                                    \
    }                                                                          \
} while (0)

    #pragma unroll 1
    for (int kb = 0; kb < 2; ++kb) {       // k = 0..7; phase = kk (static)
        #pragma unroll
        for (int kk = 0; kk < 4; ++kk) {
            SSIM_STEP(kk, 4 * kb + kk, true, (4 * kb + kk) >= 3);
        }
    }
    SSIM_STEP(0, 8, false, true);          // k=8: insert streams 32..35, emit rows 20..23
    #pragma unroll
    for (int c = 0; c < 4; ++c) { cx[c] = 0.f; cy[c] = 0.f; }
    SSIM_STEP(1, 9, false, true);          // epilogue: zero streams 36..37, emit rows 24..25

#undef SSIM_STEP

    // --- block reduction + fused global reduce (atomic) ---
    #pragma unroll
    for (int off = 32; off > 0; off >>= 1)
        acc += __shfl_down(acc, off, 64);
    int wave = t >> 6;
    if ((t & 63) == 0) red[wave] = acc;
    barrier_lds_only();
    if (t == 0) {
        float partial = red[0] + red[1] + red[2] + red[3];
        float v = partial * scale;                 // scale = -1/count
        if (band == 0 && plane == 0) v += 1.0f;    // out = 1 - sum/count
        atomicAdd(out, v);
    }
}

extern "C" void kernel_launch(void* const* d_in, const int* in_sizes, int n_in,
                              void* d_out, int out_size, void* d_ws, size_t ws_size,
                              hipStream_t stream) {
    const float* img1   = (const float*)d_in[0];
    const float* img2   = (const float*)d_in[1];
    const float* window = (const float*)d_in[2];
    float* out = (float*)d_out;

    const int planes = 16 * 9;                     // 144
    const int bands = (Hd + OUT_R - 1) / OUT_R;    // 10 (last band 22 rows)

    hipMemsetAsync(out, 0, sizeof(float), stream);

    const float scale = -(float)(1.0 / ((double)planes * Hd * Wd));
    dim3 grid(bands, planes);
    ssim_quad_kernel<<<grid, BLOCK, 0, stream>>>(img1, img2, window, out, scale);
}